// Round 1
// baseline (226.699 us; speedup 1.0000x reference)
//
#include <hip/hip_runtime.h>
#include <math.h>

#define NROWS 8192
#define NK    4096
#define NE    64

// ---------------------------------------------------------------------------
// Kernel 1: logits = x @ W^T, fp32 vector FMA, W broadcast via scalar loads.
// grid = 256 blocks (128 row-groups x 2 K-halves), block = 512 threads (8 waves)
// wave wv: rows rg*64 + lane (lane = row), all 64 experts, k in [h*2048+wv*256, +256)
// Writes partial logits part[h][row][e] (f32) to workspace.
// ---------------------------------------------------------------------------
__global__ __launch_bounds__(512) void k_gemm(const float* __restrict__ x,
                                              const float* __restrict__ W,
                                              float* __restrict__ part) {
  __shared__ float buf[4][64][65];  // stride-65 pad: bank = (lane+e)%32 -> conflict-free
  const int tid  = threadIdx.x;
  const int lane = tid & 63;
  const int wv   = __builtin_amdgcn_readfirstlane(tid >> 6);  // 0..7, wave-uniform
  const int rg   = blockIdx.x >> 1;   // 0..127
  const int h    = blockIdx.x & 1;    // K-half
  const int row  = rg * 64 + lane;
  const int k0   = h * 2048 + wv * 256;

  const float* __restrict__ xp = x + (size_t)row * NK + k0;
  const float* __restrict__ wp = W + k0;   // W[e][k] at wp[e*NK + j], uniform address

  float acc[NE];
#pragma unroll
  for (int e = 0; e < NE; ++e) acc[e] = 0.f;

  for (int t = 0; t < 16; ++t) {  // 16 tiles of 16 k
    float4 a0 = *(const float4*)(xp + t * 16 + 0);
    float4 a1 = *(const float4*)(xp + t * 16 + 4);
    float4 a2 = *(const float4*)(xp + t * 16 + 8);
    float4 a3 = *(const float4*)(xp + t * 16 + 12);
    const float xr[16] = {a0.x, a0.y, a0.z, a0.w, a1.x, a1.y, a1.z, a1.w,
                          a2.x, a2.y, a2.z, a2.w, a3.x, a3.y, a3.z, a3.w};
#pragma unroll
    for (int e = 0; e < NE; ++e) {
      const float* wr = wp + e * NK + t * 16;  // wave-uniform -> s_load_dwordx16
      float s0 = xr[0] * wr[0];
      float s1 = xr[8] * wr[8];
#pragma unroll
      for (int j = 1; j < 8; ++j) {
        s0 = fmaf(xr[j], wr[j], s0);
        s1 = fmaf(xr[j + 8], wr[j + 8], s1);
      }
      acc[e] += (s0 + s1);  // pairwise-ish combine limits rounding drift
    }
  }

  // ---- cross-wave reduction 8 -> 1 (pairwise tree, deterministic) ----
  if (wv >= 4) {
    const int b = wv - 4;
#pragma unroll
    for (int e = 0; e < NE; ++e) buf[b][lane][e] = acc[e];
  }
  __syncthreads();
  if (wv < 4) {
#pragma unroll
    for (int e = 0; e < NE; ++e) acc[e] += buf[wv][lane][e];
  }
  __syncthreads();
  if (wv == 2 || wv == 3) {
#pragma unroll
    for (int e = 0; e < NE; ++e) buf[wv - 2][lane][e] = acc[e];
  }
  __syncthreads();
  if (wv < 2) {
#pragma unroll
    for (int e = 0; e < NE; ++e) acc[e] += buf[wv][lane][e];
  }
  __syncthreads();
  if (wv == 1) {
#pragma unroll
    for (int e = 0; e < NE; ++e) buf[0][lane][e] = acc[e];
  }
  __syncthreads();
  if (wv == 0) {
#pragma unroll
    for (int e = 0; e < NE; ++e) acc[e] += buf[0][lane][e];
    float* dst = part + ((size_t)h * NROWS + row) * NE;
#pragma unroll
    for (int e = 0; e < NE; e += 4) {
      float4 v = {acc[e], acc[e + 1], acc[e + 2], acc[e + 3]};
      *(float4*)(dst + e) = v;
    }
  }
}

// ---------------------------------------------------------------------------
// Kernel 2: sum K-halves -> softmax over 64 experts (lane = expert) -> top-2
// (stable, lowest-index tie-break) -> renorm softmax -> outputs; importance
// accumulated per block, one atomicAdd per expert.
// grid = 256, block = 256 (4 waves), each wave handles 8 rows.
// ---------------------------------------------------------------------------
__global__ __launch_bounds__(256) void k_softmax(const float* __restrict__ part,
                                                 float* __restrict__ out,
                                                 float* __restrict__ imp) {
  __shared__ float simp[4][64];
  const int tid  = threadIdx.x;
  const int lane = tid & 63;
  const int wv   = tid >> 6;
  const int rbase = blockIdx.x * 32 + wv * 8;
  float impacc = 0.f;

  for (int i = 0; i < 8; ++i) {
    const int row = rbase + i;
    float lg = part[(size_t)row * NE + lane] +
               part[((size_t)NROWS + row) * NE + lane];
    // softmax across the wave (64 lanes = 64 experts)
    float m = lg;
#pragma unroll
    for (int d = 1; d < 64; d <<= 1) m = fmaxf(m, __shfl_xor(m, d));
    float p = expf(lg - m);
    float s = p;
#pragma unroll
    for (int d = 1; d < 64; d <<= 1) s += __shfl_xor(s, d);
    const float gate = p / s;
    impacc += gate;

    // top-2 via packed key: (gate bits << 32) | (63 - e); gates > 0 so float
    // bit-order == value order; ties -> lower expert index wins (jax stable).
    const unsigned long long key =
        ((unsigned long long)__float_as_uint(gate) << 32) | (unsigned)(63 - lane);
    unsigned long long k1 = key;
#pragma unroll
    for (int d = 1; d < 64; d <<= 1) {
      unsigned long long o = __shfl_xor(k1, d);
      if (o > k1) k1 = o;
    }
    const int e1 = 63 - (int)(k1 & 63ull);
    unsigned long long k2 = (lane == e1) ? 0ull : key;
#pragma unroll
    for (int d = 1; d < 64; d <<= 1) {
      unsigned long long o = __shfl_xor(k2, d);
      if (o > k2) k2 = o;
    }
    const int e2 = 63 - (int)(k2 & 63ull);

    if (lane == 0) {
      const float g1 = __uint_as_float((unsigned)(k1 >> 32));
      const float g2 = __uint_as_float((unsigned)(k2 >> 32));
      const float tt  = expf(g2 - g1);          // g1 >= g2
      const float inv = 1.f / (1.f + tt);
      out[(size_t)row * 2]     = inv;            // combine_weights
      out[(size_t)row * 2 + 1] = tt * inv;
      out[(size_t)NROWS * 2 + row * 2]     = (float)e1;  // indices as float
      out[(size_t)NROWS * 2 + row * 2 + 1] = (float)e2;
    }
  }

  simp[wv][lane] = impacc;
  __syncthreads();
  if (tid < NE) {
    const float v = simp[0][tid] + simp[1][tid] + simp[2][tid] + simp[3][tid];
    atomicAdd(&imp[tid], v);
  }
}

// ---------------------------------------------------------------------------
// Kernel 3: aux loss from importance vector (1 wave).
// ---------------------------------------------------------------------------
__global__ void k_aux(const float* __restrict__ imp, float* __restrict__ out) {
  const int lane = threadIdx.x;  // 64 threads
  const float v = imp[lane];
  float s = v;
#pragma unroll
  for (int d = 1; d < 64; d <<= 1) s += __shfl_xor(s, d);
  const float mean = s / 64.f;
  const float dv = v - mean;
  float sq = dv * dv;
#pragma unroll
  for (int d = 1; d < 64; d <<= 1) sq += __shfl_xor(sq, d);
  const float stdv = sqrtf(sq / 63.f);  // unbiased (E-1)
  const float r = stdv / (mean + 1e-6f);
  if (lane == 0) out[(size_t)NROWS * 4] = r * r;  // d_out[32768]
}

__global__ void k_zero(float* __restrict__ imp) { imp[threadIdx.x] = 0.f; }

// ---------------------------------------------------------------------------
extern "C" void kernel_launch(void* const* d_in, const int* in_sizes, int n_in,
                              void* d_out, int out_size, void* d_ws, size_t ws_size,
                              hipStream_t stream) {
  const float* x = (const float*)d_in[0];
  const float* W = (const float*)d_in[1];
  float* out  = (float*)d_out;
  float* part = (float*)d_ws;                       // 2*8192*64 f32 = 4 MB
  float* imp  = part + (size_t)2 * NROWS * NE;      // 64 f32

  hipLaunchKernelGGL(k_zero,    dim3(1),   dim3(64),  0, stream, imp);
  hipLaunchKernelGGL(k_gemm,    dim3(256), dim3(512), 0, stream, x, W, part);
  hipLaunchKernelGGL(k_softmax, dim3(256), dim3(256), 0, stream, part, out, imp);
  hipLaunchKernelGGL(k_aux,     dim3(1),   dim3(64),  0, stream, imp, out);
}